// Round 10
// baseline (868.977 us; speedup 1.0000x reference)
//
#include <hip/hip_runtime.h>
#include <hip/hip_bf16.h>

// Problem constants
#define TT 512
#define BB 256
#define II 120
#define HH 128
#define GG 512   // 4*H
#define D1 512
#define NOUT 7
#define TB (TT*BB)  // 131072

typedef _Float16 f16x2 __attribute__((ext_vector_type(2)));
typedef _Float16 f16x4 __attribute__((ext_vector_type(4)));
typedef _Float16 f16x8 __attribute__((ext_vector_type(8)));
typedef float    f32x4 __attribute__((ext_vector_type(4)));

// ---------- static device scratch ----------
__device__ unsigned short g_xg[(size_t)TB * GG];   // [T*B, 512] bf16
__device__ _Float16       g_h0[(size_t)TB * HH];   // [T*B, 128] f16
__device__ float          g_pooled[BB * HH];

// ---------- helpers ----------
__device__ inline float bf2f(unsigned short u) {
    return __uint_as_float(((unsigned)u) << 16);
}
__device__ inline unsigned short f2bf(float f) {
    unsigned u = __float_as_uint(f);
    return (unsigned short)((u + 0x7fffu + ((u >> 16) & 1u)) >> 16);
}
__device__ inline float sigm(float x) {
    return 1.0f / (1.0f + __expf(-x));
}
__device__ inline float tanh_fast(float x) {
    x = fminf(fmaxf(x, -15.f), 15.f);
    float e = __expf(2.f * x);
    return (e - 1.f) / (e + 1.f);
}
// DECISIVE EXPERIMENT (r10): force the single-instruction dot product.
// If r3-r9 were silently lowering __builtin_amdgcn_fdot2 / float fallback to
// cvt+fma chains (4-6 VALU ops per dot2), this is a ~2x issue-rate win in the
// recurrence. v_dot2_f32_f16: D = A.x*B.x + A.y*B.y + C (f16 in, f32 accum).
__device__ inline float fdot2(f16x2 a, f16x2 b, float c) {
    float d;
    asm("v_dot2_f32_f16 %0, %1, %2, %3"
        : "=v"(d)
        : "v"(a), "v"(b), "v"(c));
    return d;
}
// quad lane-xor moves via DPP quad_perm (pure VALU, no LDS pipe)
__device__ inline float dpp_xor1(float v) {
#if __has_builtin(__builtin_amdgcn_mov_dpp)
    return __int_as_float(
        __builtin_amdgcn_mov_dpp(__float_as_int(v), 0xB1, 0xf, 0xf, true)); // [1,0,3,2]
#else
    return __shfl_xor(v, 1, 4);
#endif
}
__device__ inline float dpp_xor2(float v) {
#if __has_builtin(__builtin_amdgcn_mov_dpp)
    return __int_as_float(
        __builtin_amdgcn_mov_dpp(__float_as_int(v), 0x4E, 0xf, 0xf, true)); // [2,3,0,1]
#else
    return __shfl_xor(v, 2, 4);
#endif
}
template <int L>
__device__ inline float qb(float v) {
#if __has_builtin(__builtin_amdgcn_mov_dpp)
    return __int_as_float(
        __builtin_amdgcn_mov_dpp(__float_as_int(v), L * 0x55, 0xf, 0xf, true));
#else
    return __shfl(v, L, 4);
#endif
}

// ---------- MFMA GEMM: xg[n,g] = sum_k A[n,k]*W[g,k] + bia[g]+bib[g] ----------
// f16 MFMA 16x16x32. Block: 128(M)x128(N), 512 threads = 8 waves (2x4 of 64x32).
// A: LAYER0 = x (f32->f16 on stage), LAYER1 = g_h0 (f16). B = W rows (f32->f16).
template <int LAYER>
__global__ __launch_bounds__(512) void gemm_mfma_kernel(
    const float* __restrict__ A0,     // [TB, II] (LAYER 0 only)
    const float* __restrict__ W,      // [512, F] f32
    const float* __restrict__ bia,
    const float* __restrict__ bib)
{
    const int F  = (LAYER == 0) ? II : HH;
    const int m0 = blockIdx.x * 128;
    const int n0 = blockIdx.y * 128;
    const int t    = threadIdx.x;
    const int lane = t & 63;
    const int wv   = t >> 6;         // 0..7
    const int wm   = wv >> 2;        // 0..1 -> rows wm*64
    const int wn   = wv & 3;         // 0..3 -> cols wn*32
    const int l15  = lane & 15;
    const int lhi  = lane >> 4;      // 0..3

    __shared__ _Float16 As[128][40];
    __shared__ _Float16 Bs[128][40];

    f32x4 acc[4][2];
#pragma unroll
    for (int mi = 0; mi < 4; ++mi)
#pragma unroll
        for (int ni = 0; ni < 2; ++ni)
            acc[mi][ni] = f32x4{0.f, 0.f, 0.f, 0.f};

    const int srow = t >> 2;   // staging row 0..127
    const int q    = t & 3;    // k-slot: covers k0+q*8 .. +7

#pragma unroll 1
    for (int kc = 0; kc < 4; ++kc) {
        const int k0 = kc * 32;
        if (LAYER == 0) {
#pragma unroll
            for (int h = 0; h < 2; ++h) {
                int k = k0 + q * 8 + h * 4;
                float4 v = make_float4(0.f, 0.f, 0.f, 0.f);
                if (k + 4 <= F) v = *(const float4*)&A0[(size_t)(m0 + srow) * II + k];
                f16x4 hv = {(_Float16)v.x, (_Float16)v.y, (_Float16)v.z, (_Float16)v.w};
                *(f16x4*)&As[srow][q * 8 + h * 4] = hv;
            }
        } else {
            int k = k0 + q * 8;   // F=128: always valid
            f16x8 v = *(const f16x8*)&g_h0[(size_t)(m0 + srow) * HH + k];
            *(f16x8*)&As[srow][q * 8] = v;
        }
#pragma unroll
        for (int h = 0; h < 2; ++h) {
            int k = k0 + q * 8 + h * 4;
            float4 v = make_float4(0.f, 0.f, 0.f, 0.f);
            if (k + 4 <= F) v = *(const float4*)&W[(size_t)(n0 + srow) * F + k];
            f16x4 hv = {(_Float16)v.x, (_Float16)v.y, (_Float16)v.z, (_Float16)v.w};
            *(f16x4*)&Bs[srow][q * 8 + h * 4] = hv;
        }
        __syncthreads();

        f16x8 af[4], bf[2];
#pragma unroll
        for (int mi = 0; mi < 4; ++mi)
            af[mi] = *(const f16x8*)&As[wm * 64 + mi * 16 + l15][lhi * 8];
#pragma unroll
        for (int ni = 0; ni < 2; ++ni)
            bf[ni] = *(const f16x8*)&Bs[wn * 32 + ni * 16 + l15][lhi * 8];
#pragma unroll
        for (int mi = 0; mi < 4; ++mi)
#pragma unroll
            for (int ni = 0; ni < 2; ++ni)
                acc[mi][ni] = __builtin_amdgcn_mfma_f32_16x16x32_f16(
                    af[mi], bf[ni], acc[mi][ni], 0, 0, 0);
        __syncthreads();
    }

#pragma unroll
    for (int ni = 0; ni < 2; ++ni) {
        const int col = n0 + wn * 32 + ni * 16 + l15;
        const float bc = bia[col] + bib[col];
#pragma unroll
        for (int mi = 0; mi < 4; ++mi) {
#pragma unroll
            for (int j = 0; j < 4; ++j) {
                const int grow = m0 + wm * 64 + mi * 16 + lhi * 4 + j;
                g_xg[(size_t)grow * GG + col] = f2bf(acc[mi][ni][j] + bc);
            }
        }
    }
}

// ---------- LSTM recurrence, quad-k-split (r8 structure, asm v_dot2) ----------
// Thread t -> (unit u = t>>2, quad lane p = t&3).
// Weights (64 VGPR): slot j = gate (p^j), k in [32p, 32p+32) (XOR-rotated).
// Per step: 4x ds_read_b128, 64 v_dot2 in 4 indep chains, 3 DPP-xor combines,
// DPP quad broadcast of gates, 1 barrier. x prefetched 1 step ahead (global).
template <int LAYER>
__global__ __launch_bounds__(512) void lstm_kernel(
    const float* __restrict__ Whh,   // [512,128]
    const int* __restrict__ lens)
{
    const int b = blockIdx.x;
    const int t = threadIdx.x;
    const int u = t >> 2;
    const int p = t & 3;

    __shared__ __align__(16) _Float16 h_lds[2][HH];

    f16x2 w[4][16];
#pragma unroll
    for (int j = 0; j < 4; ++j) {
        const int row = ((p ^ j) << 7) + u;          // gate (p^j), unit u
#pragma unroll
        for (int k4 = 0; k4 < 8; ++k4) {
            float4 v = *(const float4*)&Whh[(size_t)row * HH + (p << 5) + k4 * 4];
            w[j][k4 * 2 + 0] = f16x2{(_Float16)v.x, (_Float16)v.y};
            w[j][k4 * 2 + 1] = f16x2{(_Float16)v.z, (_Float16)v.w};
        }
    }
    if (t < HH) {
        h_lds[0][t] = (_Float16)0.f;
        h_lds[1][t] = (_Float16)0.f;
    }
    float c = 0.f, pool = 0.f;
    const int len = lens[b];
    __syncthreads();

    const unsigned short* xp = g_xg + (size_t)b * GG + (p * 128 + u);
    const size_t xstride = (size_t)BB * GG;
    float xcur = bf2f(xp[0]);

    for (int step = 0; step < TT; ++step) {
        float xnext = (step + 1 < TT) ? bf2f(xp[(size_t)(step + 1) * xstride]) : 0.f;
        const int rd = step & 1, wr = rd ^ 1;

        float pa0 = 0.f, pa1 = 0.f, pa2 = 0.f, pa3 = 0.f;
#pragma unroll
        for (int seg = 0; seg < 4; ++seg) {
            f16x8 hv = *(const f16x8*)&h_lds[rd][(p << 5) + seg * 8];
            f16x2 h01 = {hv[0], hv[1]}, h23 = {hv[2], hv[3]};
            f16x2 h45 = {hv[4], hv[5]}, h67 = {hv[6], hv[7]};
            pa0 = fdot2(w[0][seg * 4 + 0], h01, pa0);
            pa0 = fdot2(w[0][seg * 4 + 1], h23, pa0);
            pa0 = fdot2(w[0][seg * 4 + 2], h45, pa0);
            pa0 = fdot2(w[0][seg * 4 + 3], h67, pa0);
            pa1 = fdot2(w[1][seg * 4 + 0], h01, pa1);
            pa1 = fdot2(w[1][seg * 4 + 1], h23, pa1);
            pa1 = fdot2(w[1][seg * 4 + 2], h45, pa1);
            pa1 = fdot2(w[1][seg * 4 + 3], h67, pa1);
            pa2 = fdot2(w[2][seg * 4 + 0], h01, pa2);
            pa2 = fdot2(w[2][seg * 4 + 1], h23, pa2);
            pa2 = fdot2(w[2][seg * 4 + 2], h45, pa2);
            pa2 = fdot2(w[2][seg * 4 + 3], h67, pa2);
            pa3 = fdot2(w[3][seg * 4 + 0], h01, pa3);
            pa3 = fdot2(w[3][seg * 4 + 1], h23, pa3);
            pa3 = fdot2(w[3][seg * 4 + 2], h45, pa3);
            pa3 = fdot2(w[3][seg * 4 + 3], h67, pa3);
        }
        // quad transpose-combine: lane p ends with gate p's full dot
        pa0 += dpp_xor1(pa1);
        pa2 += dpp_xor1(pa3);
        pa0 += dpp_xor2(pa2);

        float acc = pa0 + xcur;
        float act = (p == 2) ? tanh_fast(acc) : sigm(acc);
        float i_ = qb<0>(act), f_ = qb<1>(act), g_ = qb<2>(act), o_ = qb<3>(act);
        c = f_ * c + i_ * g_;
        float hvv = o_ * tanh_fast(c);

        if (LAYER == 0) {
            if (p == 0) g_h0[((size_t)step * BB + b) * HH + u] = (_Float16)hvv;
        } else {
            if (step < len) {
                float ah = fabsf(hvv);
                pool += ah * sqrtf(ah);   // |h|^1.5
            }
        }
        if (p == 0) h_lds[wr][u] = (_Float16)hvv;
        __syncthreads();
        xcur = xnext;
    }

    if (LAYER == 1 && p == 0) {
        float s = powf(pool, 2.f / 3.f) * powf((float)len, -2.f / 3.f);
        g_pooled[b * HH + u] = s;
    }
}

// ---------- MLP + softmax ----------
__global__ __launch_bounds__(512) void mlp_kernel(
    const float* __restrict__ W1, const float* __restrict__ b1,
    const float* __restrict__ W2, const float* __restrict__ b2,
    float* __restrict__ out)
{
    const int b = blockIdx.x;
    const int t = threadIdx.x;
    __shared__ __align__(16) float pl[HH];
    __shared__ float x1[D1];
    __shared__ float lg[NOUT];

    if (t < HH) pl[t] = g_pooled[b * HH + t];
    __syncthreads();

    float acc = b1[t];
#pragma unroll
    for (int k4 = 0; k4 < 32; ++k4) {
        float4 wv = *(const float4*)&W1[(size_t)t * HH + k4 * 4];
        float4 pv = *(const float4*)&pl[k4 * 4];
        acc += wv.x * pv.x + wv.y * pv.y + wv.z * pv.z + wv.w * pv.w;
    }
    x1[t] = fmaxf(acc, 0.f);
    __syncthreads();

    if (t < NOUT) {
        float a = b2[t];
        for (int d = 0; d < D1; ++d) a += x1[d] * W2[(size_t)t * D1 + d];
        lg[t] = a;
    }
    __syncthreads();
    if (t < NOUT) {
        float m = lg[0];
#pragma unroll
        for (int j = 1; j < NOUT; ++j) m = fmaxf(m, lg[j]);
        float s = 0.f;
#pragma unroll
        for (int j = 0; j < NOUT; ++j) s += __expf(lg[j] - m);
        out[b * NOUT + t] = __expf(lg[t] - m) / s;
    }
}

// ---------- launch ----------
extern "C" void kernel_launch(void* const* d_in, const int* in_sizes, int n_in,
                              void* d_out, int out_size, void* d_ws, size_t ws_size,
                              hipStream_t stream)
{
    const float* x      = (const float*)d_in[0];
    const int*   lens   = (const int*)d_in[1];
    const float* W_ih0  = (const float*)d_in[2];
    const float* W_hh0  = (const float*)d_in[3];
    const float* b_ih0  = (const float*)d_in[4];
    const float* b_hh0  = (const float*)d_in[5];
    const float* W_ih1  = (const float*)d_in[6];
    const float* W_hh1  = (const float*)d_in[7];
    const float* b_ih1  = (const float*)d_in[8];
    const float* b_hh1  = (const float*)d_in[9];
    const float* W1     = (const float*)d_in[10];
    const float* b1     = (const float*)d_in[11];
    const float* W2     = (const float*)d_in[12];
    const float* b2     = (const float*)d_in[13];
    float* out = (float*)d_out;

    dim3 gg(TB / 128, GG / 128);   // (1024, 4)
    gemm_mfma_kernel<0><<<gg, 512, 0, stream>>>(x, W_ih0, b_ih0, b_hh0);
    lstm_kernel<0><<<BB, 512, 0, stream>>>(W_hh0, lens);
    gemm_mfma_kernel<1><<<gg, 512, 0, stream>>>(x, W_ih1, b_ih1, b_hh1);
    lstm_kernel<1><<<BB, 512, 0, stream>>>(W_hh1, lens);
    mlp_kernel<<<BB, 512, 0, stream>>>(W1, b1, W2, b2, out);
}

// Round 11
// 672.673 us; speedup vs baseline: 1.2918x; 1.2918x over previous
//
#include <hip/hip_runtime.h>
#include <hip/hip_bf16.h>

// Problem constants
#define TT 512
#define BB 256
#define II 120
#define HH 128
#define GG 512   // 4*H
#define D1 512
#define NOUT 7
#define TB (TT*BB)  // 131072

typedef _Float16 f16x2 __attribute__((ext_vector_type(2)));
typedef _Float16 f16x4 __attribute__((ext_vector_type(4)));
typedef _Float16 f16x8 __attribute__((ext_vector_type(8)));
typedef float    f32x4 __attribute__((ext_vector_type(4)));

// ---------- static device scratch ----------
__device__ unsigned short g_xg[(size_t)TB * GG];   // [T*B, 512] bf16
__device__ _Float16       g_h0[(size_t)TB * HH];   // [T*B, 128] f16
__device__ float          g_pooled[BB * HH];

// ---------- helpers ----------
__device__ inline float bf2f(unsigned short u) {
    return __uint_as_float(((unsigned)u) << 16);
}
__device__ inline unsigned short f2bf(float f) {
    unsigned u = __float_as_uint(f);
    return (unsigned short)((u + 0x7fffu + ((u >> 16) & 1u)) >> 16);
}
// builtin dot2 (r10: asm version was equal-or-worse due to copy movs)
__device__ inline float fdot2(f16x2 a, f16x2 b, float c) {
#if __has_builtin(__builtin_amdgcn_fdot2)
    return __builtin_amdgcn_fdot2(a, b, c, false);
#else
    return c + (float)a[0] * (float)b[0] + (float)a[1] * (float)b[1];
#endif
}
// DPP pair swap within quads: [1,0,3,2] — lanes 2u <-> 2u+1
__device__ inline float dpp_xor1(float v) {
#if __has_builtin(__builtin_amdgcn_mov_dpp)
    return __int_as_float(
        __builtin_amdgcn_mov_dpp(__float_as_int(v), 0xB1, 0xf, 0xf, true));
#else
    return __shfl_xor(v, 1, 4);
#endif
}

// ---------- MFMA GEMM: xg[n,g] = sum_k A[n,k]*W[g,k] + bia[g]+bib[g] ----------
// f16 MFMA 16x16x32. Block: 128(M)x128(N), 512 threads = 8 waves (2x4 of 64x32).
template <int LAYER>
__global__ __launch_bounds__(512) void gemm_mfma_kernel(
    const float* __restrict__ A0,     // [TB, II] (LAYER 0 only)
    const float* __restrict__ W,      // [512, F] f32
    const float* __restrict__ bia,
    const float* __restrict__ bib)
{
    const int F  = (LAYER == 0) ? II : HH;
    const int m0 = blockIdx.x * 128;
    const int n0 = blockIdx.y * 128;
    const int t    = threadIdx.x;
    const int lane = t & 63;
    const int wv   = t >> 6;         // 0..7
    const int wm   = wv >> 2;        // 0..1 -> rows wm*64
    const int wn   = wv & 3;         // 0..3 -> cols wn*32
    const int l15  = lane & 15;
    const int lhi  = lane >> 4;      // 0..3

    __shared__ _Float16 As[128][40];
    __shared__ _Float16 Bs[128][40];

    f32x4 acc[4][2];
#pragma unroll
    for (int mi = 0; mi < 4; ++mi)
#pragma unroll
        for (int ni = 0; ni < 2; ++ni)
            acc[mi][ni] = f32x4{0.f, 0.f, 0.f, 0.f};

    const int srow = t >> 2;   // staging row 0..127
    const int q    = t & 3;    // k-slot: covers k0+q*8 .. +7

#pragma unroll 1
    for (int kc = 0; kc < 4; ++kc) {
        const int k0 = kc * 32;
        if (LAYER == 0) {
#pragma unroll
            for (int h = 0; h < 2; ++h) {
                int k = k0 + q * 8 + h * 4;
                float4 v = make_float4(0.f, 0.f, 0.f, 0.f);
                if (k + 4 <= F) v = *(const float4*)&A0[(size_t)(m0 + srow) * II + k];
                f16x4 hv = {(_Float16)v.x, (_Float16)v.y, (_Float16)v.z, (_Float16)v.w};
                *(f16x4*)&As[srow][q * 8 + h * 4] = hv;
            }
        } else {
            int k = k0 + q * 8;   // F=128: always valid
            f16x8 v = *(const f16x8*)&g_h0[(size_t)(m0 + srow) * HH + k];
            *(f16x8*)&As[srow][q * 8] = v;
        }
#pragma unroll
        for (int h = 0; h < 2; ++h) {
            int k = k0 + q * 8 + h * 4;
            float4 v = make_float4(0.f, 0.f, 0.f, 0.f);
            if (k + 4 <= F) v = *(const float4*)&W[(size_t)(n0 + srow) * F + k];
            f16x4 hv = {(_Float16)v.x, (_Float16)v.y, (_Float16)v.z, (_Float16)v.w};
            *(f16x4*)&Bs[srow][q * 8 + h * 4] = hv;
        }
        __syncthreads();

        f16x8 af[4], bf[2];
#pragma unroll
        for (int mi = 0; mi < 4; ++mi)
            af[mi] = *(const f16x8*)&As[wm * 64 + mi * 16 + l15][lhi * 8];
#pragma unroll
        for (int ni = 0; ni < 2; ++ni)
            bf[ni] = *(const f16x8*)&Bs[wn * 32 + ni * 16 + l15][lhi * 8];
#pragma unroll
        for (int mi = 0; mi < 4; ++mi)
#pragma unroll
            for (int ni = 0; ni < 2; ++ni)
                acc[mi][ni] = __builtin_amdgcn_mfma_f32_16x16x32_f16(
                    af[mi], bf[ni], acc[mi][ni], 0, 0, 0);
        __syncthreads();
    }

#pragma unroll
    for (int ni = 0; ni < 2; ++ni) {
        const int col = n0 + wn * 32 + ni * 16 + l15;
        const float bc = bia[col] + bib[col];
#pragma unroll
        for (int mi = 0; mi < 4; ++mi) {
#pragma unroll
            for (int j = 0; j < 4; ++j) {
                const int grow = m0 + wm * 64 + mi * 16 + lhi * 4 + j;
                g_xg[(size_t)grow * GG + col] = f2bf(acc[mi][ni][j] + bc);
            }
        }
    }
}

// ---------- LSTM recurrence: 256 threads, 1 wave/SIMD ----------
// r8's 512-thread version ran 2 phase-locked waves/SIMD: step = 2x issue +
// exposed stalls (measured 1780 cyc; VALUBusy ~60% = 2x550 issue + ~680 stall).
// The barrier-locked second wave serialized issue without hiding stalls.
// Here: 256 threads (4 waves, 1/SIMD). Thread t -> (u = t>>1, q = t&1):
//   q=0 owns gate rows {u (i), 128+u (f)}; q=1 owns {256+u (g), 384+u (o)}.
// Full K=128 per row: weights 2x64 f16x2 = 128 VGPR (cap 256 at 256t: safe).
// h reads are pure LDS broadcasts (all lanes same address). Gate exchange =
// ONE DPP pair swap. Activations: branchless single-exp (tanh = 2*sigm(2x)-1
// via per-lane constants). Stores split across q lanes. 1 barrier/step.
template <int LAYER>
__global__ __launch_bounds__(256) void lstm_kernel(
    const float* __restrict__ Whh,   // [512,128]
    const int* __restrict__ lens)
{
    const int b = blockIdx.x;
    const int t = threadIdx.x;
    const int u = t >> 1;        // unit 0..127
    const int q = t & 1;         // row-pair selector
    const int r0 = q * 256 + u;  // i (q=0) or g (q=1)
    const int r1 = r0 + 128;     // f (q=0) or o (q=1)

    __shared__ __align__(16) _Float16 h_lds[2][HH];

    f16x2 w0[64], w1[64];
#pragma unroll
    for (int k4 = 0; k4 < 32; ++k4) {
        float4 v = *(const float4*)&Whh[(size_t)r0 * HH + k4 * 4];
        w0[k4 * 2 + 0] = f16x2{(_Float16)v.x, (_Float16)v.y};
        w0[k4 * 2 + 1] = f16x2{(_Float16)v.z, (_Float16)v.w};
        float4 v2 = *(const float4*)&Whh[(size_t)r1 * HH + k4 * 4];
        w1[k4 * 2 + 0] = f16x2{(_Float16)v2.x, (_Float16)v2.y};
        w1[k4 * 2 + 1] = f16x2{(_Float16)v2.z, (_Float16)v2.w};
    }
    if (t < HH) {
        h_lds[0][t] = (_Float16)0.f;
        h_lds[1][t] = (_Float16)0.f;
    }
    float c = 0.f, pool = 0.f;
    const int len = lens[b];
    __syncthreads();

    const unsigned short* xb = g_xg + (size_t)b * GG;
    const size_t xstride = (size_t)BB * GG;
    float x0 = bf2f(xb[r0]);
    float x1 = bf2f(xb[r1]);

    // act0: q=0 -> sigm(x) ; q=1 -> tanh(x) = 2*sigm(2x)-1 (branchless)
    const float am = q ? 2.f : 1.f;    // input scale
    const float as = q ? 2.f : 1.f;    // output scale
    const float ao = q ? -1.f : 0.f;   // output offset

    for (int step = 0; step < TT; ++step) {
        float nx0 = 0.f, nx1 = 0.f;
        if (step + 1 < TT) {
            const unsigned short* xn = xb + (size_t)(step + 1) * xstride;
            nx0 = bf2f(xn[r0]);
            nx1 = bf2f(xn[r1]);
        }
        const int rd = step & 1, wr = rd ^ 1;

        // two full-K dots, 8 independent 8-deep chains
        float a00 = 0.f, a01 = 0.f, a02 = 0.f, a03 = 0.f;
        float a10 = 0.f, a11 = 0.f, a12 = 0.f, a13 = 0.f;
#pragma unroll
        for (int seg = 0; seg < 8; ++seg) {
            f16x8 hv = *(const f16x8*)&h_lds[rd][seg * 8];   // broadcast read
            f16x2 hA = {hv[0], hv[1]}, hB = {hv[2], hv[3]};
            f16x2 hC = {hv[4], hv[5]}, hD = {hv[6], hv[7]};
            a00 = fdot2(w0[seg * 4 + 0], hA, a00);
            a01 = fdot2(w0[seg * 4 + 1], hB, a01);
            a02 = fdot2(w0[seg * 4 + 2], hC, a02);
            a03 = fdot2(w0[seg * 4 + 3], hD, a03);
            a10 = fdot2(w1[seg * 4 + 0], hA, a10);
            a11 = fdot2(w1[seg * 4 + 1], hB, a11);
            a12 = fdot2(w1[seg * 4 + 2], hC, a12);
            a13 = fdot2(w1[seg * 4 + 3], hD, a13);
        }
        const float a0 = (a00 + a01) + (a02 + a03) + x0;
        const float a1 = (a10 + a11) + (a12 + a13) + x1;

        // activations (branchless): act0 = sigm/tanh, act1 = sigm
        const float s0 = 1.f / (1.f + __expf(-(a0 * am)));
        const float act0 = s0 * as + ao;
        const float act1 = 1.f / (1.f + __expf(-a1));

        // pair exchange: (u,0) has i,f ; (u,1) has g,o
        const float p0 = dpp_xor1(act0);
        const float p1 = dpp_xor1(act1);
        const float i_ = q ? p0 : act0;
        const float f_ = q ? p1 : act1;
        const float g_ = q ? act0 : p0;
        const float o_ = q ? act1 : p1;

        c = f_ * c + i_ * g_;
        const float e2 = __expf(-2.f * c);
        const float th = 2.f / (1.f + e2) - 1.f;
        const float hv2 = o_ * th;

        if (LAYER == 0) {
            if (q) g_h0[((size_t)step * BB + b) * HH + u] = (_Float16)hv2;
        } else {
            if (step < len) {
                const float ah = fabsf(hv2);
                pool += ah * sqrtf(ah);   // |h|^1.5
            }
        }
        if (!q) h_lds[wr][u] = (_Float16)hv2;
        __syncthreads();
        x0 = nx0;
        x1 = nx1;
    }

    if (LAYER == 1 && !q) {
        const float s = powf(pool, 2.f / 3.f) * powf((float)len, -2.f / 3.f);
        g_pooled[b * HH + u] = s;
    }
}

// ---------- MLP + softmax ----------
__global__ __launch_bounds__(512) void mlp_kernel(
    const float* __restrict__ W1, const float* __restrict__ b1,
    const float* __restrict__ W2, const float* __restrict__ b2,
    float* __restrict__ out)
{
    const int b = blockIdx.x;
    const int t = threadIdx.x;
    __shared__ __align__(16) float pl[HH];
    __shared__ float x1[D1];
    __shared__ float lg[NOUT];

    if (t < HH) pl[t] = g_pooled[b * HH + t];
    __syncthreads();

    float acc = b1[t];
#pragma unroll
    for (int k4 = 0; k4 < 32; ++k4) {
        float4 wv = *(const float4*)&W1[(size_t)t * HH + k4 * 4];
        float4 pv = *(const float4*)&pl[k4 * 4];
        acc += wv.x * pv.x + wv.y * pv.y + wv.z * pv.z + wv.w * pv.w;
    }
    x1[t] = fmaxf(acc, 0.f);
    __syncthreads();

    if (t < NOUT) {
        float a = b2[t];
        for (int d = 0; d < D1; ++d) a += x1[d] * W2[(size_t)t * D1 + d];
        lg[t] = a;
    }
    __syncthreads();
    if (t < NOUT) {
        float m = lg[0];
#pragma unroll
        for (int j = 1; j < NOUT; ++j) m = fmaxf(m, lg[j]);
        float s = 0.f;
#pragma unroll
        for (int j = 0; j < NOUT; ++j) s += __expf(lg[j] - m);
        out[b * NOUT + t] = __expf(lg[t] - m) / s;
    }
}

// ---------- launch ----------
extern "C" void kernel_launch(void* const* d_in, const int* in_sizes, int n_in,
                              void* d_out, int out_size, void* d_ws, size_t ws_size,
                              hipStream_t stream)
{
    const float* x      = (const float*)d_in[0];
    const int*   lens   = (const int*)d_in[1];
    const float* W_ih0  = (const float*)d_in[2];
    const float* W_hh0  = (const float*)d_in[3];
    const float* b_ih0  = (const float*)d_in[4];
    const float* b_hh0  = (const float*)d_in[5];
    const float* W_ih1  = (const float*)d_in[6];
    const float* W_hh1  = (const float*)d_in[7];
    const float* b_ih1  = (const float*)d_in[8];
    const float* b_hh1  = (const float*)d_in[9];
    const float* W1     = (const float*)d_in[10];
    const float* b1     = (const float*)d_in[11];
    const float* W2     = (const float*)d_in[12];
    const float* b2     = (const float*)d_in[13];
    float* out = (float*)d_out;

    dim3 gg(TB / 128, GG / 128);   // (1024, 4)
    gemm_mfma_kernel<0><<<gg, 512, 0, stream>>>(x, W_ih0, b_ih0, b_hh0);
    lstm_kernel<0><<<BB, 256, 0, stream>>>(W_hh0, lens);
    gemm_mfma_kernel<1><<<gg, 512, 0, stream>>>(x, W_ih1, b_ih1, b_hh1);
    lstm_kernel<1><<<BB, 256, 0, stream>>>(W_hh1, lens);
    mlp_kernel<<<BB, 512, 0, stream>>>(W1, b1, W2, b2, out);
}